// Round 11
// baseline (440.208 us; speedup 1.0000x reference)
//
#include <hip/hip_runtime.h>
#include <hip/hip_fp16.h>
#include <math.h>

// SPAIRPointFeatureNetwork on MI355X.
//   h_{p,j} = Q[j] - G[p];  celu monotonic => segmax(celu(h)) = celu(max_j Q[j] - G[p]).
//
// R10 post-mortem: ~50KB-LDS blocks only get ~1.3 resident/CU (measured across
// R8/R9/R10) -> latency-bound at 55us/layer. R11: channel-plane processing
// (FH=32 = 2 sequential 16-ch planes over one 24.6KB rows buffer, q3 stored
// planar) cuts LDS to ~31KB -> 4 blocks x 8 waves/CU; finish runs 4 thr/point.

#define NPTS 65536
#define KNBR 64
#define GRES 16
#define NCELL 4096   // 16^3

__device__ __forceinline__ float celu1(float x) {
    return x > 0.0f ? x : (__expf(x) - 1.0f);
}

__device__ __forceinline__ unsigned pkmax(unsigned a, unsigned b) {
    unsigned d;
    asm("v_pk_max_f16 %0, %1, %2" : "=v"(d) : "v"(a), "v"(b));
    return d;
}

__device__ __forceinline__ unsigned pack2(float a, float b) {
    __half2 h = __floats2half2_rn(a, b);
    return *(unsigned*)&h;
}

__device__ __forceinline__ int cell_of(float p0, float p1, float p2) {
    int cx = min((int)(p0 * 16.0f), 15);
    int cy = min((int)(p1 * 16.0f), 15);
    int cz = min((int)(p2 * 16.0f), 15);
    return (cx * GRES + cy) * GRES + cz;
}

// ---- sort pipeline ----

__global__ __launch_bounds__(256) void k_zero(int* __restrict__ buf) {
    buf[blockIdx.x * 256 + threadIdx.x] = 0;   // counts + cursor
}

__global__ __launch_bounds__(256) void k_hist(
    const float* __restrict__ pos, int* __restrict__ counts)
{
    int t = blockIdx.x * 256 + threadIdx.x;
    if (t >= NPTS) return;
    int cid = cell_of(pos[3 * t], pos[3 * t + 1], pos[3 * t + 2]);
    atomicAdd(&counts[cid], 1);
}

__global__ void k_scan(const int* __restrict__ counts, int* __restrict__ starts) {
    int lane = threadIdx.x;             // 64 lanes x 64 cells
    const int4* cp = (const int4*)counts;
    int4 c[16];
#pragma unroll
    for (int k = 0; k < 16; ++k) c[k] = cp[lane * 16 + k];
    int T = 0;
#pragma unroll
    for (int k = 0; k < 16; ++k) T += c[k].x + c[k].y + c[k].z + c[k].w;
    int inc = T;
#pragma unroll
    for (int d = 1; d < 64; d <<= 1) {
        int u = __shfl_up(inc, d, 64);
        if (lane >= d) inc += u;
    }
    int run = inc - T;
    int4* sp = (int4*)starts;
#pragma unroll
    for (int k = 0; k < 16; ++k) {
        int4 v = c[k], o;
        o.x = run; run += v.x;
        o.y = run; run += v.y;
        o.z = run; run += v.z;
        o.w = run; run += v.w;
        sp[lane * 16 + k] = o;
    }
}

__global__ __launch_bounds__(256) void k_slot(
    const float* __restrict__ pos,
    const int* __restrict__ starts, int* __restrict__ cursor,
    unsigned* __restrict__ cellslot, int* __restrict__ perm,
    float* __restrict__ pos_s,
    const float* __restrict__ w1a, const float* __restrict__ b1a,
    __half* __restrict__ q1,
    float* __restrict__ dout, int out_size)
{
    int t = blockIdx.x * 256 + threadIdx.x;
    if (t >= NPTS) return;
    float p0 = pos[3 * t + 0];
    float p1 = pos[3 * t + 1];
    float p2 = pos[3 * t + 2];
    dout[3 * t + 0] = p0;
    dout[3 * t + 1] = p1;
    dout[3 * t + 2] = p2;
    for (int j = 35 * NPTS + t; j < out_size; j += NPTS)
        dout[j] = 0.0f;

    int cid = cell_of(p0, p1, p2);
    int s = starts[cid] + atomicAdd(&cursor[cid], 1);
    cellslot[t] = ((unsigned)cid << 16) | (unsigned)s;
    perm[s] = t;
    pos_s[3 * s + 0] = p0;
    pos_s[3 * s + 1] = p1;
    pos_s[3 * s + 2] = p2;

    float q[8];
#pragma unroll
    for (int c = 0; c < 8; ++c) {
        float a = b1a[c];
        a = fmaf(p0, w1a[0 * 8 + c] + w1a[3 * 8 + c], a);
        a = fmaf(p1, w1a[1 * 8 + c] + w1a[4 * 8 + c], a);
        a = fmaf(p2, w1a[2 * 8 + c] + w1a[5 * 8 + c], a);
        q[c] = a;
    }
    uint4 pk;
    pk.x = pack2(q[0], q[1]);
    pk.y = pack2(q[2], q[3]);
    pk.z = pack2(q[4], q[5]);
    pk.w = pack2(q[6], q[7]);
    *(uint4*)(q1 + 8 * s) = pk;
}

// remap edges to neighborhood-local slots: one random 4B gather per edge.
__global__ __launch_bounds__(256) void k_remap(
    const int* __restrict__ idx,
    const int* __restrict__ perm,
    const unsigned* __restrict__ cellslot,
    const int* __restrict__ starts,
    const int* __restrict__ counts,
    unsigned short* __restrict__ es)
{
    __shared__ int s_start[27];
    __shared__ int s_pfx[28];
    int cid = blockIdx.x;
    if (threadIdx.x < 64) {
        int lane = threadIdx.x;
        int cnt = 0, st = 0;
        if (lane < 27) {
            int cx = cid >> 8, cy = (cid >> 4) & 15, cz = cid & 15;
            int dx = lane / 9 - 1, dy = (lane / 3) % 3 - 1, dz = lane % 3 - 1;
            int nx = cx + dx, ny = cy + dy, nz = cz + dz;
            bool ok = ((unsigned)nx < 16u) && ((unsigned)ny < 16u) && ((unsigned)nz < 16u);
            if (ok) {
                int nc = (((nx << 4) | ny) << 4) | nz;
                cnt = counts[nc];
                st  = starts[nc];
            }
        }
        int inc = cnt;
#pragma unroll
        for (int d = 1; d < 32; d <<= 1) {
            int u = __shfl_up(inc, d, 64);
            if (lane >= d) inc += u;
        }
        if (lane < 27) { s_start[lane] = st; s_pfx[lane] = inc - cnt; }
        if (lane == 26) s_pfx[27] = inc;
    }
    __syncthreads();

    int base = starts[cid];
    int P = counts[cid];
    int cx = cid >> 8, cy = (cid >> 4) & 15, cz = cid & 15;
    int tasks = P * 64;
    for (int task = threadIdx.x; task < tasks; task += 256) {
        int p_s = base + (task >> 6);
        int e = task & 63;
        int orig = perm[p_s];
        int j_orig = idx[orig * 64 + e];
        unsigned csj = cellslot[j_orig];
        int j_s = (int)(csj & 0xFFFFu);
        int jc  = (int)(csj >> 16);
        int r = ((jc >> 8) - cx + 1) * 9 + (((jc >> 4) & 15) - cy + 1) * 3 + ((jc & 15) - cz + 1);
        es[p_s * 64 + e] = (unsigned short)(s_pfx[r] + (j_s - s_start[r]));
    }
}

// ---- fused layer, per-cell, 512 threads, channel-planes ----
// FH = FHP*NH input channels processed as NH sequential planes of FHP channels
// over one small rows buffer. SL = FHP/8 16B-slices per plane-row.
template <int FHP, int NH, int FOUT, int FHN, int QNPL, bool WRITEX, int SCAP, int MCAP>
__global__ __launch_bounds__(512, 8) void k_layer(
    const __half* __restrict__ q,    // NH planes, each sorted N x FHP
    const unsigned short* __restrict__ es,
    const float* __restrict__ pos_s,
    const int* __restrict__ starts,
    const int* __restrict__ counts,
    const int* __restrict__ perm,
    const float* __restrict__ wap,   // 3 x FH
    const float* __restrict__ wb,    // FH x FOUT
    const float* __restrict__ bb,    // FOUT
    const float* __restrict__ wan,   // (FOUT+3) x FHN or null
    const float* __restrict__ ban,   // FHN or null
    float* __restrict__ xout,        // WRITEX only
    __half* __restrict__ qnext)      // !WRITEX only, QNPL planes
{
    constexpr int SL   = FHP / 8;                // 1 or 2
    constexpr int PS   = (SL == 1) ? 1 : 3;      // padded stride: (3s+c)%8 covers all positions
    constexpr int FH   = FHP * NH;
    constexpr int EPL  = 4 * SL;                 // edges per lane per point (4 or 8)
    constexpr int ER   = EPL / 2;
    constexpr int CHUNKS = (SCAP * SL + 511) / 512;
    const long long PLANE = (long long)NPTS * FHP;

    __shared__ int s_start[27];
    __shared__ int s_pfx[28];
    __shared__ int row_src[SCAP];
    __shared__ uint4 rows[SCAP * PS];
    __shared__ uint4 m_lds[MCAP * NH * SL];

    int cid  = blockIdx.x;
    int base = starts[cid];
    int P    = counts[cid];

    // phase A: wave0 builds descriptor + slot->source-row table (LDS only)
    if (threadIdx.x < 64) {
        int lane = threadIdx.x;
        int cnt = 0, st = 0;
        if (lane < 27) {
            int cx = cid >> 8, cy = (cid >> 4) & 15, cz = cid & 15;
            int dx = lane / 9 - 1, dy = (lane / 3) % 3 - 1, dz = lane % 3 - 1;
            int nx = cx + dx, ny = cy + dy, nz = cz + dz;
            bool ok = ((unsigned)nx < 16u) && ((unsigned)ny < 16u) && ((unsigned)nz < 16u);
            if (ok) {
                int nc = (((nx << 4) | ny) << 4) | nz;
                cnt = counts[nc];
                st  = starts[nc];
            }
        }
        int inc = cnt;
#pragma unroll
        for (int d = 1; d < 32; d <<= 1) {
            int u = __shfl_up(inc, d, 64);
            if (lane >= d) inc += u;
        }
        if (lane < 27) {
            int b0 = inc - cnt;
            s_start[lane] = st;
            s_pfx[lane]   = b0;
            for (int k = 0; k < cnt; ++k)
                if (b0 + k < SCAP) row_src[b0 + k] = st + k;
        }
        if (lane == 26) s_pfx[27] = inc;
    }

    int w    = threadIdx.x >> 6;
    int lane = threadIdx.x & 63;
    int u    = lane & 15;
    int c    = u % SL;
    int g    = u / SL;
    int pl   = w * 4 + (lane >> 4);    // 16 lanes per point, 32 points covered

    unsigned er[ER];
    if (pl < P) {   // prefetch es before the barrier (no LDS dependency)
        const void* ep = (const void*)(es + (long long)(base + pl) * 64 + g * EPL);
        if constexpr (ER == 2) {
            uint2 t = *(const uint2*)ep; er[0] = t.x; er[1] = t.y;
        } else {
            uint4 t = *(const uint4*)ep;
            er[0] = t.x; er[1] = t.y; er[2] = t.z; er[3] = t.w;
        }
    }
    __syncthreads();
    int stot = min(s_pfx[27], SCAP);

    for (int h = 0; h < NH; ++h) {
        const __half* qh = q + (long long)h * PLANE;
        // stage plane h: register-batched independent loads
        {
            int ee[CHUNKS], sr[CHUNKS];
            uint4 vv[CHUNKS];
#pragma unroll
            for (int cc = 0; cc < CHUNKS; ++cc) {
                ee[cc] = (int)threadIdx.x + cc * 512;
                sr[cc] = (ee[cc] < stot * SL) ? row_src[ee[cc] / SL] : -1;
            }
#pragma unroll
            for (int cc = 0; cc < CHUNKS; ++cc)
                if (sr[cc] >= 0)
                    vv[cc] = *((const uint4*)(qh + (long long)sr[cc] * FHP) + (ee[cc] % SL));
#pragma unroll
            for (int cc = 0; cc < CHUNKS; ++cc)
                if (sr[cc] >= 0)
                    rows[(ee[cc] / SL) * PS + (ee[cc] % SL)] = vv[cc];
        }
        __syncthreads();

        // edge max for this plane
        for (int p0i = 0; p0i < P; p0i += 32) {
            int plx = p0i + w * 4 + (lane >> 4);
            unsigned e2[ER];
            if (p0i == 0) {
#pragma unroll
                for (int k = 0; k < ER; ++k) e2[k] = er[k];
            } else if (plx < P) {   // rare: cells with P > 32
                const void* ep = (const void*)(es + (long long)(base + plx) * 64 + g * EPL);
                if constexpr (ER == 2) {
                    uint2 t = *(const uint2*)ep; e2[0] = t.x; e2[1] = t.y;
                } else {
                    uint4 t = *(const uint4*)ep;
                    e2[0] = t.x; e2[1] = t.y; e2[2] = t.z; e2[3] = t.w;
                }
            }
            if (plx < P) {
                unsigned ax = 0xFC00FC00u, ay = 0xFC00FC00u, az = 0xFC00FC00u, aw = 0xFC00FC00u;
#pragma unroll
                for (int k0 = 0; k0 < EPL; k0 += 4) {
                    uint4 v[4];
#pragma unroll
                    for (int k = 0; k < 4; ++k) {
                        int kk = k0 + k;
                        int s = (int)((e2[kk >> 1] >> ((kk & 1) * 16)) & 0xFFFFu);
                        if (s < stot) {
                            v[k] = rows[s * PS + c];
                        } else {   // overflow fallback (statistically never)
                            int r = 0;
                            while (s >= s_pfx[r + 1]) ++r;
                            int rg = s_start[r] + (s - s_pfx[r]);
                            v[k] = *((const uint4*)(qh + (long long)rg * FHP) + c);
                        }
                    }
#pragma unroll
                    for (int k = 0; k < 4; ++k) {
                        ax = pkmax(ax, v[k].x); ay = pkmax(ay, v[k].y);
                        az = pkmax(az, v[k].z); aw = pkmax(aw, v[k].w);
                    }
                }
#pragma unroll
                for (int st = SL; st < 16; st <<= 1) {
                    ax = pkmax(ax, (unsigned)__shfl_xor((int)ax, st, 64));
                    ay = pkmax(ay, (unsigned)__shfl_xor((int)ay, st, 64));
                    az = pkmax(az, (unsigned)__shfl_xor((int)az, st, 64));
                    aw = pkmax(aw, (unsigned)__shfl_xor((int)aw, st, 64));
                }
                if (g == 0 && plx < MCAP) {
                    uint4 r4; r4.x = ax; r4.y = ay; r4.z = az; r4.w = aw;
                    m_lds[plx * (NH * SL) + h * SL + c] = r4;
                }
            }
        }
        __syncthreads();
    }

    // phase D: finish, 4 threads/point (redundant x, split outputs)
    int PM = min(P, MCAP);
    for (int tq = threadIdx.x; tq < PM * 4; tq += 512) {
        int lt = tq >> 2, j = tq & 3;
        int p = base + lt;
        float p0 = pos_s[3 * p + 0];
        float p1 = pos_s[3 * p + 1];
        float p2 = pos_s[3 * p + 2];
        float hv[FH];
#pragma unroll
        for (int k = 0; k < NH * SL; ++k) {
            uint4 vv = m_lds[lt * (NH * SL) + k];
            unsigned w4[4] = {vv.x, vv.y, vv.z, vv.w};
#pragma unroll
            for (int kk = 0; kk < 4; ++kk) {
                float2 f = __half22float2(*(__half2*)&w4[kk]);
                hv[k * 8 + kk * 2 + 0] = f.x;
                hv[k * 8 + kk * 2 + 1] = f.y;
            }
        }
#pragma unroll
        for (int ch = 0; ch < FH; ++ch) {
            float gg = p0 * wap[ch] + p1 * wap[FH + ch] + p2 * wap[2 * FH + ch];
            hv[ch] = celu1(hv[ch] - gg);
        }
        float x[FOUT];
#pragma unroll
        for (int c2 = 0; c2 < FOUT; ++c2) {
            float a = bb[c2];
#pragma unroll
            for (int ch = 0; ch < FH; ++ch)
                a = fmaf(hv[ch], wb[ch * FOUT + c2], a);
            x[c2] = celu1(a);
        }
        if constexpr (WRITEX) {
            int orig = perm[p];
            float4* xo = (float4*)(xout + (long long)orig * FOUT + j * 8);
            xo[0] = make_float4(x[j * 8 + 0], x[j * 8 + 1], x[j * 8 + 2], x[j * 8 + 3]);
            xo[1] = make_float4(x[j * 8 + 4], x[j * 8 + 5], x[j * 8 + 6], x[j * 8 + 7]);
        } else {
            constexpr int CPT = FHN / 4;        // qnext channels per thread (4 or 8)
            constexpr int PCH = FHN / QNPL;     // channels per output plane
            int cn0 = j * CPT;
            int pn  = cn0 / PCH;
            int co  = cn0 - pn * PCH;
            float qn[CPT];
#pragma unroll
            for (int jj = 0; jj < CPT; ++jj) {
                int cn = cn0 + jj;
                float a = ban[cn];
#pragma unroll
                for (int c2 = 0; c2 < FOUT; ++c2)
                    a = fmaf(x[c2], wan[c2 * FHN + cn], a);
                a = fmaf(p0, wan[(FOUT + 0) * FHN + cn], a);
                a = fmaf(p1, wan[(FOUT + 1) * FHN + cn], a);
                a = fmaf(p2, wan[(FOUT + 2) * FHN + cn], a);
                qn[jj] = a;
            }
            __half* dstp = qnext + (long long)pn * NPTS * PCH + (long long)p * PCH + co;
            if constexpr (CPT == 4) {
                uint2 pk;
                pk.x = pack2(qn[0], qn[1]);
                pk.y = pack2(qn[2], qn[3]);
                *(uint2*)dstp = pk;
            } else {
                uint4 pk;
                pk.x = pack2(qn[0], qn[1]);
                pk.y = pack2(qn[2], qn[3]);
                pk.z = pack2(qn[4], qn[5]);
                pk.w = pack2(qn[6], qn[7]);
                *(uint4*)dstp = pk;
            }
        }
    }
}

extern "C" void kernel_launch(void* const* d_in, const int* in_sizes, int n_in,
                              void* d_out, int out_size, void* d_ws, size_t ws_size,
                              hipStream_t stream) {
    const float* pos = (const float*)d_in[0];
    const int* idx = (const int*)d_in[4];   // in_index, int32 per harness contract
    const float* w1a = (const float*)d_in[5];
    const float* b1a = (const float*)d_in[6];
    const float* w1b = (const float*)d_in[7];
    const float* b1b = (const float*)d_in[8];
    const float* w2a = (const float*)d_in[9];
    const float* b2a = (const float*)d_in[10];
    const float* w2b = (const float*)d_in[11];
    const float* b2b = (const float*)d_in[12];
    const float* w3a = (const float*)d_in[13];
    const float* b3a = (const float*)d_in[14];
    const float* w3b = (const float*)d_in[15];
    const float* b3b = (const float*)d_in[16];
    float* out = (float*)d_out;

    char* ws = (char*)d_ws;
    unsigned short* es = (unsigned short*)ws;                     // 8 MB
    __half* q1         = (__half*)(ws + (8u << 20));              // 1 MB
    __half* q2         = (__half*)(ws + (9u << 20));              // 2 MB
    __half* q3         = (__half*)(ws + (11u << 20));             // 4 MB (2 planar 16-ch planes)
    float*  pos_s      = (float*)(ws + (15u << 20));              // 768 KB
    unsigned* cellslot = (unsigned*)(ws + (16u << 20));           // 256 KB
    int*    perm       = (int*)(ws + (16u << 20) + (256u << 10)); // 256 KB
    int*    counts     = (int*)(ws + (17u << 20));                // 16 KB
    int*    cursor     = counts + NCELL;                          // 16 KB
    int*    starts     = cursor + NCELL;                          // 16 KB

    k_zero<<<2 * NCELL / 256, 256, 0, stream>>>(counts);
    k_hist<<<NPTS / 256, 256, 0, stream>>>(pos, counts);
    k_scan<<<1, 64, 0, stream>>>(counts, starts);
    k_slot<<<NPTS / 256, 256, 0, stream>>>(pos, starts, cursor, cellslot, perm,
                                           pos_s, w1a, b1a, q1, out, out_size);
    k_remap<<<NCELL, 256, 0, stream>>>(idx, perm, cellslot, starts, counts, es);

    // layer 1: FHP=8, NH=1  (LDS ~11.5 KB) -> q2 single plane
    k_layer<8, 1, 8, 16, 1, false, 512, 64><<<NCELL, 512, 0, stream>>>(
        q1, es, pos_s, starts, counts, perm,
        w1a + 3 * 8, w1b, b1b, w2a, b2a, nullptr, q2);
    // layer 2: FHP=16, NH=1 (LDS ~29.7 KB) -> q3 as 2 planar 16-ch planes
    k_layer<16, 1, 16, 32, 2, false, 512, 64><<<NCELL, 512, 0, stream>>>(
        q2, es, pos_s, starts, counts, perm,
        w2a + 8 * 16, w2b, b2b, w3a, b3a, nullptr, q3);
    // layer 3: FHP=16, NH=2 (LDS ~31 KB) -> final x (FHN/QNPL dummies, WRITEX)
    k_layer<16, 2, 32, 16, 1, true, 512, 64><<<NCELL, 512, 0, stream>>>(
        q3, es, pos_s, starts, counts, perm,
        w3a + 16 * 32, w3b, b3b, nullptr, nullptr, out + 3 * NPTS, nullptr);
}

// Round 12
// 264.261 us; speedup vs baseline: 1.6658x; 1.6658x over previous
//
#include <hip/hip_runtime.h>
#include <hip/hip_fp16.h>
#include <math.h>

// SPAIRPointFeatureNetwork on MI355X.
//   h_{p,j} = Q[j] - G[p];  celu monotonic => segmax(celu(h)) = celu(max_j Q[j] - G[p]).
//
// R11 post-mortem: __launch_bounds__(512,8) capped VGPR at 64 -> compiler
// spilled the finish phase to scratch (WRITE_SIZE 204 MB, FETCH 110 MB of
// spill traffic = the whole 250us). R12: bounds (512,4) (VGPR<=128, expect
// ~64-80 actual -> 3 blocks x 8 waves = 24 waves/CU with 31KB LDS), and the
// WRITEX finish computes only its own 8 channels.

#define NPTS 65536
#define KNBR 64
#define GRES 16
#define NCELL 4096   // 16^3

__device__ __forceinline__ float celu1(float x) {
    return x > 0.0f ? x : (__expf(x) - 1.0f);
}

__device__ __forceinline__ unsigned pkmax(unsigned a, unsigned b) {
    unsigned d;
    asm("v_pk_max_f16 %0, %1, %2" : "=v"(d) : "v"(a), "v"(b));
    return d;
}

__device__ __forceinline__ unsigned pack2(float a, float b) {
    __half2 h = __floats2half2_rn(a, b);
    return *(unsigned*)&h;
}

__device__ __forceinline__ int cell_of(float p0, float p1, float p2) {
    int cx = min((int)(p0 * 16.0f), 15);
    int cy = min((int)(p1 * 16.0f), 15);
    int cz = min((int)(p2 * 16.0f), 15);
    return (cx * GRES + cy) * GRES + cz;
}

// ---- sort pipeline ----

__global__ __launch_bounds__(256) void k_zero(int* __restrict__ buf) {
    buf[blockIdx.x * 256 + threadIdx.x] = 0;   // counts + cursor
}

__global__ __launch_bounds__(256) void k_hist(
    const float* __restrict__ pos, int* __restrict__ counts)
{
    int t = blockIdx.x * 256 + threadIdx.x;
    if (t >= NPTS) return;
    int cid = cell_of(pos[3 * t], pos[3 * t + 1], pos[3 * t + 2]);
    atomicAdd(&counts[cid], 1);
}

__global__ void k_scan(const int* __restrict__ counts, int* __restrict__ starts) {
    int lane = threadIdx.x;             // 64 lanes x 64 cells
    const int4* cp = (const int4*)counts;
    int4 c[16];
#pragma unroll
    for (int k = 0; k < 16; ++k) c[k] = cp[lane * 16 + k];
    int T = 0;
#pragma unroll
    for (int k = 0; k < 16; ++k) T += c[k].x + c[k].y + c[k].z + c[k].w;
    int inc = T;
#pragma unroll
    for (int d = 1; d < 64; d <<= 1) {
        int u = __shfl_up(inc, d, 64);
        if (lane >= d) inc += u;
    }
    int run = inc - T;
    int4* sp = (int4*)starts;
#pragma unroll
    for (int k = 0; k < 16; ++k) {
        int4 v = c[k], o;
        o.x = run; run += v.x;
        o.y = run; run += v.y;
        o.z = run; run += v.z;
        o.w = run; run += v.w;
        sp[lane * 16 + k] = o;
    }
}

__global__ __launch_bounds__(256) void k_slot(
    const float* __restrict__ pos,
    const int* __restrict__ starts, int* __restrict__ cursor,
    unsigned* __restrict__ cellslot, int* __restrict__ perm,
    float* __restrict__ pos_s,
    const float* __restrict__ w1a, const float* __restrict__ b1a,
    __half* __restrict__ q1,
    float* __restrict__ dout, int out_size)
{
    int t = blockIdx.x * 256 + threadIdx.x;
    if (t >= NPTS) return;
    float p0 = pos[3 * t + 0];
    float p1 = pos[3 * t + 1];
    float p2 = pos[3 * t + 2];
    dout[3 * t + 0] = p0;
    dout[3 * t + 1] = p1;
    dout[3 * t + 2] = p2;
    for (int j = 35 * NPTS + t; j < out_size; j += NPTS)
        dout[j] = 0.0f;

    int cid = cell_of(p0, p1, p2);
    int s = starts[cid] + atomicAdd(&cursor[cid], 1);
    cellslot[t] = ((unsigned)cid << 16) | (unsigned)s;
    perm[s] = t;
    pos_s[3 * s + 0] = p0;
    pos_s[3 * s + 1] = p1;
    pos_s[3 * s + 2] = p2;

    float q[8];
#pragma unroll
    for (int c = 0; c < 8; ++c) {
        float a = b1a[c];
        a = fmaf(p0, w1a[0 * 8 + c] + w1a[3 * 8 + c], a);
        a = fmaf(p1, w1a[1 * 8 + c] + w1a[4 * 8 + c], a);
        a = fmaf(p2, w1a[2 * 8 + c] + w1a[5 * 8 + c], a);
        q[c] = a;
    }
    uint4 pk;
    pk.x = pack2(q[0], q[1]);
    pk.y = pack2(q[2], q[3]);
    pk.z = pack2(q[4], q[5]);
    pk.w = pack2(q[6], q[7]);
    *(uint4*)(q1 + 8 * s) = pk;
}

// remap edges to neighborhood-local slots: one random 4B gather per edge.
__global__ __launch_bounds__(256) void k_remap(
    const int* __restrict__ idx,
    const int* __restrict__ perm,
    const unsigned* __restrict__ cellslot,
    const int* __restrict__ starts,
    const int* __restrict__ counts,
    unsigned short* __restrict__ es)
{
    __shared__ int s_start[27];
    __shared__ int s_pfx[28];
    int cid = blockIdx.x;
    if (threadIdx.x < 64) {
        int lane = threadIdx.x;
        int cnt = 0, st = 0;
        if (lane < 27) {
            int cx = cid >> 8, cy = (cid >> 4) & 15, cz = cid & 15;
            int dx = lane / 9 - 1, dy = (lane / 3) % 3 - 1, dz = lane % 3 - 1;
            int nx = cx + dx, ny = cy + dy, nz = cz + dz;
            bool ok = ((unsigned)nx < 16u) && ((unsigned)ny < 16u) && ((unsigned)nz < 16u);
            if (ok) {
                int nc = (((nx << 4) | ny) << 4) | nz;
                cnt = counts[nc];
                st  = starts[nc];
            }
        }
        int inc = cnt;
#pragma unroll
        for (int d = 1; d < 32; d <<= 1) {
            int u = __shfl_up(inc, d, 64);
            if (lane >= d) inc += u;
        }
        if (lane < 27) { s_start[lane] = st; s_pfx[lane] = inc - cnt; }
        if (lane == 26) s_pfx[27] = inc;
    }
    __syncthreads();

    int base = starts[cid];
    int P = counts[cid];
    int cx = cid >> 8, cy = (cid >> 4) & 15, cz = cid & 15;
    int tasks = P * 64;
    for (int task = threadIdx.x; task < tasks; task += 256) {
        int p_s = base + (task >> 6);
        int e = task & 63;
        int orig = perm[p_s];
        int j_orig = idx[orig * 64 + e];
        unsigned csj = cellslot[j_orig];
        int j_s = (int)(csj & 0xFFFFu);
        int jc  = (int)(csj >> 16);
        int r = ((jc >> 8) - cx + 1) * 9 + (((jc >> 4) & 15) - cy + 1) * 3 + ((jc & 15) - cz + 1);
        es[p_s * 64 + e] = (unsigned short)(s_pfx[r] + (j_s - s_start[r]));
    }
}

// ---- fused layer, per-cell, 512 threads, channel-planes ----
// FH = FHP*NH input channels processed as NH sequential planes of FHP channels
// over one small rows buffer. SL = FHP/8 16B-slices per plane-row.
template <int FHP, int NH, int FOUT, int FHN, int QNPL, bool WRITEX, int SCAP, int MCAP>
__global__ __launch_bounds__(512, 4) void k_layer(
    const __half* __restrict__ q,    // NH planes, each sorted N x FHP
    const unsigned short* __restrict__ es,
    const float* __restrict__ pos_s,
    const int* __restrict__ starts,
    const int* __restrict__ counts,
    const int* __restrict__ perm,
    const float* __restrict__ wap,   // 3 x FH
    const float* __restrict__ wb,    // FH x FOUT
    const float* __restrict__ bb,    // FOUT
    const float* __restrict__ wan,   // (FOUT+3) x FHN or null
    const float* __restrict__ ban,   // FHN or null
    float* __restrict__ xout,        // WRITEX only
    __half* __restrict__ qnext)      // !WRITEX only, QNPL planes
{
    constexpr int SL   = FHP / 8;                // 1 or 2
    constexpr int PS   = (SL == 1) ? 1 : 3;      // padded stride: (3s+c)%8 covers all positions
    constexpr int FH   = FHP * NH;
    constexpr int EPL  = 4 * SL;                 // edges per lane per point (4 or 8)
    constexpr int ER   = EPL / 2;
    constexpr int CHUNKS = (SCAP * SL + 511) / 512;
    const long long PLANE = (long long)NPTS * FHP;

    __shared__ int s_start[27];
    __shared__ int s_pfx[28];
    __shared__ int row_src[SCAP];
    __shared__ uint4 rows[SCAP * PS];
    __shared__ uint4 m_lds[MCAP * NH * SL];

    int cid  = blockIdx.x;
    int base = starts[cid];
    int P    = counts[cid];

    // phase A: wave0 builds descriptor + slot->source-row table (LDS only)
    if (threadIdx.x < 64) {
        int lane = threadIdx.x;
        int cnt = 0, st = 0;
        if (lane < 27) {
            int cx = cid >> 8, cy = (cid >> 4) & 15, cz = cid & 15;
            int dx = lane / 9 - 1, dy = (lane / 3) % 3 - 1, dz = lane % 3 - 1;
            int nx = cx + dx, ny = cy + dy, nz = cz + dz;
            bool ok = ((unsigned)nx < 16u) && ((unsigned)ny < 16u) && ((unsigned)nz < 16u);
            if (ok) {
                int nc = (((nx << 4) | ny) << 4) | nz;
                cnt = counts[nc];
                st  = starts[nc];
            }
        }
        int inc = cnt;
#pragma unroll
        for (int d = 1; d < 32; d <<= 1) {
            int u = __shfl_up(inc, d, 64);
            if (lane >= d) inc += u;
        }
        if (lane < 27) {
            int b0 = inc - cnt;
            s_start[lane] = st;
            s_pfx[lane]   = b0;
            for (int k = 0; k < cnt; ++k)
                if (b0 + k < SCAP) row_src[b0 + k] = st + k;
        }
        if (lane == 26) s_pfx[27] = inc;
    }

    int w    = threadIdx.x >> 6;
    int lane = threadIdx.x & 63;
    int u    = lane & 15;
    int c    = u % SL;
    int g    = u / SL;
    int pl   = w * 4 + (lane >> 4);    // 16 lanes per point, 32 points covered

    unsigned er[ER];
    if (pl < P) {   // prefetch es before the barrier (no LDS dependency)
        const void* ep = (const void*)(es + (long long)(base + pl) * 64 + g * EPL);
        if constexpr (ER == 2) {
            uint2 t = *(const uint2*)ep; er[0] = t.x; er[1] = t.y;
        } else {
            uint4 t = *(const uint4*)ep;
            er[0] = t.x; er[1] = t.y; er[2] = t.z; er[3] = t.w;
        }
    }
    __syncthreads();
    int stot = min(s_pfx[27], SCAP);

    for (int h = 0; h < NH; ++h) {
        const __half* qh = q + (long long)h * PLANE;
        // stage plane h: register-batched independent loads
        {
            int ee[CHUNKS], sr[CHUNKS];
            uint4 vv[CHUNKS];
#pragma unroll
            for (int cc = 0; cc < CHUNKS; ++cc) {
                ee[cc] = (int)threadIdx.x + cc * 512;
                sr[cc] = (ee[cc] < stot * SL) ? row_src[ee[cc] / SL] : -1;
            }
#pragma unroll
            for (int cc = 0; cc < CHUNKS; ++cc)
                if (sr[cc] >= 0)
                    vv[cc] = *((const uint4*)(qh + (long long)sr[cc] * FHP) + (ee[cc] % SL));
#pragma unroll
            for (int cc = 0; cc < CHUNKS; ++cc)
                if (sr[cc] >= 0)
                    rows[(ee[cc] / SL) * PS + (ee[cc] % SL)] = vv[cc];
        }
        __syncthreads();

        // edge max for this plane
        for (int p0i = 0; p0i < P; p0i += 32) {
            int plx = p0i + w * 4 + (lane >> 4);
            unsigned e2[ER];
            if (p0i == 0) {
#pragma unroll
                for (int k = 0; k < ER; ++k) e2[k] = er[k];
            } else if (plx < P) {   // rare: cells with P > 32
                const void* ep = (const void*)(es + (long long)(base + plx) * 64 + g * EPL);
                if constexpr (ER == 2) {
                    uint2 t = *(const uint2*)ep; e2[0] = t.x; e2[1] = t.y;
                } else {
                    uint4 t = *(const uint4*)ep;
                    e2[0] = t.x; e2[1] = t.y; e2[2] = t.z; e2[3] = t.w;
                }
            }
            if (plx < P) {
                unsigned ax = 0xFC00FC00u, ay = 0xFC00FC00u, az = 0xFC00FC00u, aw = 0xFC00FC00u;
#pragma unroll
                for (int k0 = 0; k0 < EPL; k0 += 4) {
                    uint4 v[4];
#pragma unroll
                    for (int k = 0; k < 4; ++k) {
                        int kk = k0 + k;
                        int s = (int)((e2[kk >> 1] >> ((kk & 1) * 16)) & 0xFFFFu);
                        if (s < stot) {
                            v[k] = rows[s * PS + c];
                        } else {   // overflow fallback (statistically never)
                            int r = 0;
                            while (s >= s_pfx[r + 1]) ++r;
                            int rg = s_start[r] + (s - s_pfx[r]);
                            v[k] = *((const uint4*)(qh + (long long)rg * FHP) + c);
                        }
                    }
#pragma unroll
                    for (int k = 0; k < 4; ++k) {
                        ax = pkmax(ax, v[k].x); ay = pkmax(ay, v[k].y);
                        az = pkmax(az, v[k].z); aw = pkmax(aw, v[k].w);
                    }
                }
#pragma unroll
                for (int st = SL; st < 16; st <<= 1) {
                    ax = pkmax(ax, (unsigned)__shfl_xor((int)ax, st, 64));
                    ay = pkmax(ay, (unsigned)__shfl_xor((int)ay, st, 64));
                    az = pkmax(az, (unsigned)__shfl_xor((int)az, st, 64));
                    aw = pkmax(aw, (unsigned)__shfl_xor((int)aw, st, 64));
                }
                if (g == 0 && plx < MCAP) {
                    uint4 r4; r4.x = ax; r4.y = ay; r4.z = az; r4.w = aw;
                    m_lds[plx * (NH * SL) + h * SL + c] = r4;
                }
            }
        }
        __syncthreads();
    }

    // phase D: finish, 4 threads/point
    int PM = min(P, MCAP);
    for (int tq = threadIdx.x; tq < PM * 4; tq += 512) {
        int lt = tq >> 2, j = tq & 3;
        int p = base + lt;
        float p0 = pos_s[3 * p + 0];
        float p1 = pos_s[3 * p + 1];
        float p2 = pos_s[3 * p + 2];
        float hv[FH];
#pragma unroll
        for (int k = 0; k < NH * SL; ++k) {
            uint4 vv = m_lds[lt * (NH * SL) + k];
            unsigned w4[4] = {vv.x, vv.y, vv.z, vv.w};
#pragma unroll
            for (int kk = 0; kk < 4; ++kk) {
                float2 f = __half22float2(*(__half2*)&w4[kk]);
                hv[k * 8 + kk * 2 + 0] = f.x;
                hv[k * 8 + kk * 2 + 1] = f.y;
            }
        }
#pragma unroll
        for (int ch = 0; ch < FH; ++ch) {
            float gg = p0 * wap[ch] + p1 * wap[FH + ch] + p2 * wap[2 * FH + ch];
            hv[ch] = celu1(hv[ch] - gg);
        }
        if constexpr (WRITEX) {
            // only this thread's 8 output channels (keeps live set small)
            float x8[8];
#pragma unroll
            for (int jj = 0; jj < 8; ++jj) {
                int c2 = j * 8 + jj;
                float a = bb[c2];
#pragma unroll
                for (int ch = 0; ch < FH; ++ch)
                    a = fmaf(hv[ch], wb[ch * FOUT + c2], a);
                x8[jj] = celu1(a);
            }
            int orig = perm[p];
            float4* xo = (float4*)(xout + (long long)orig * FOUT + j * 8);
            xo[0] = make_float4(x8[0], x8[1], x8[2], x8[3]);
            xo[1] = make_float4(x8[4], x8[5], x8[6], x8[7]);
        } else {
            float x[FOUT];
#pragma unroll
            for (int c2 = 0; c2 < FOUT; ++c2) {
                float a = bb[c2];
#pragma unroll
                for (int ch = 0; ch < FH; ++ch)
                    a = fmaf(hv[ch], wb[ch * FOUT + c2], a);
                x[c2] = celu1(a);
            }
            constexpr int CPT = FHN / 4;        // qnext channels per thread (4 or 8)
            constexpr int PCH = FHN / QNPL;     // channels per output plane
            int cn0 = j * CPT;
            int pn  = cn0 / PCH;
            int co  = cn0 - pn * PCH;
            float qn[CPT];
#pragma unroll
            for (int jj = 0; jj < CPT; ++jj) {
                int cn = cn0 + jj;
                float a = ban[cn];
#pragma unroll
                for (int c2 = 0; c2 < FOUT; ++c2)
                    a = fmaf(x[c2], wan[c2 * FHN + cn], a);
                a = fmaf(p0, wan[(FOUT + 0) * FHN + cn], a);
                a = fmaf(p1, wan[(FOUT + 1) * FHN + cn], a);
                a = fmaf(p2, wan[(FOUT + 2) * FHN + cn], a);
                qn[jj] = a;
            }
            __half* dstp = qnext + (long long)pn * NPTS * PCH + (long long)p * PCH + co;
            if constexpr (CPT == 4) {
                uint2 pk;
                pk.x = pack2(qn[0], qn[1]);
                pk.y = pack2(qn[2], qn[3]);
                *(uint2*)dstp = pk;
            } else {
                uint4 pk;
                pk.x = pack2(qn[0], qn[1]);
                pk.y = pack2(qn[2], qn[3]);
                pk.z = pack2(qn[4], qn[5]);
                pk.w = pack2(qn[6], qn[7]);
                *(uint4*)dstp = pk;
            }
        }
    }
}

extern "C" void kernel_launch(void* const* d_in, const int* in_sizes, int n_in,
                              void* d_out, int out_size, void* d_ws, size_t ws_size,
                              hipStream_t stream) {
    const float* pos = (const float*)d_in[0];
    const int* idx = (const int*)d_in[4];   // in_index, int32 per harness contract
    const float* w1a = (const float*)d_in[5];
    const float* b1a = (const float*)d_in[6];
    const float* w1b = (const float*)d_in[7];
    const float* b1b = (const float*)d_in[8];
    const float* w2a = (const float*)d_in[9];
    const float* b2a = (const float*)d_in[10];
    const float* w2b = (const float*)d_in[11];
    const float* b2b = (const float*)d_in[12];
    const float* w3a = (const float*)d_in[13];
    const float* b3a = (const float*)d_in[14];
    const float* w3b = (const float*)d_in[15];
    const float* b3b = (const float*)d_in[16];
    float* out = (float*)d_out;

    char* ws = (char*)d_ws;
    unsigned short* es = (unsigned short*)ws;                     // 8 MB
    __half* q1         = (__half*)(ws + (8u << 20));              // 1 MB
    __half* q2         = (__half*)(ws + (9u << 20));              // 2 MB
    __half* q3         = (__half*)(ws + (11u << 20));             // 4 MB (2 planar 16-ch planes)
    float*  pos_s      = (float*)(ws + (15u << 20));              // 768 KB
    unsigned* cellslot = (unsigned*)(ws + (16u << 20));           // 256 KB
    int*    perm       = (int*)(ws + (16u << 20) + (256u << 10)); // 256 KB
    int*    counts     = (int*)(ws + (17u << 20));                // 16 KB
    int*    cursor     = counts + NCELL;                          // 16 KB
    int*    starts     = cursor + NCELL;                          // 16 KB

    k_zero<<<2 * NCELL / 256, 256, 0, stream>>>(counts);
    k_hist<<<NPTS / 256, 256, 0, stream>>>(pos, counts);
    k_scan<<<1, 64, 0, stream>>>(counts, starts);
    k_slot<<<NPTS / 256, 256, 0, stream>>>(pos, starts, cursor, cellslot, perm,
                                           pos_s, w1a, b1a, q1, out, out_size);
    k_remap<<<NCELL, 256, 0, stream>>>(idx, perm, cellslot, starts, counts, es);

    // layer 1: FHP=8, NH=1  (LDS ~11.5 KB) -> q2 single plane
    k_layer<8, 1, 8, 16, 1, false, 512, 64><<<NCELL, 512, 0, stream>>>(
        q1, es, pos_s, starts, counts, perm,
        w1a + 3 * 8, w1b, b1b, w2a, b2a, nullptr, q2);
    // layer 2: FHP=16, NH=1 (LDS ~29.7 KB) -> q3 as 2 planar 16-ch planes
    k_layer<16, 1, 16, 32, 2, false, 512, 64><<<NCELL, 512, 0, stream>>>(
        q2, es, pos_s, starts, counts, perm,
        w2a + 8 * 16, w2b, b2b, w3a, b3a, nullptr, q3);
    // layer 3: FHP=16, NH=2 (LDS ~31 KB) -> final x
    k_layer<16, 2, 32, 16, 1, true, 512, 64><<<NCELL, 512, 0, stream>>>(
        q3, es, pos_s, starts, counts, perm,
        w3a + 16 * 32, w3b, b3b, nullptr, nullptr, out + 3 * NPTS, nullptr);
}